// Round 1
// baseline (539.972 us; speedup 1.0000x reference)
//
#include <hip/hip_runtime.h>
#include <hip/hip_bf16.h>

#define B_ 16
#define C_ 256
#define N_ 9216
#define NCH 144  // N_/64

using short8 = __attribute__((ext_vector_type(8))) short;
using f32x4  = __attribute__((ext_vector_type(4))) float;

// Kernel A: per-(b, 64-col chunk): LayerNorm stats over C, normalize, write bf16 xn,
// accumulate xbar[b][c] = sum_n xn[b][c][n] via wave-reduce + atomics.
__global__ __launch_bounds__(256) void kA_lnorm(const float* __restrict__ x,
    const float* __restrict__ ln_w, const float* __restrict__ ln_b,
    __hip_bfloat16* __restrict__ xn, float* __restrict__ xbar) {
  __shared__ float red1[4][64], red2[4][64], mu_s[64], r_s[64], lw[C_], lb[C_];
  const int t = threadIdx.x;
  const int b = blockIdx.x / NCH;
  const int n0 = (blockIdx.x % NCH) * 64;
  const int j = t & 63, cg = t >> 6;
  if (t < C_) { lw[t] = ln_w[t]; lb[t] = ln_b[t]; }
  const float* xb = x + (size_t)b * C_ * N_ + n0;
  float vals[64];
  float s1 = 0.f, s2 = 0.f;
#pragma unroll
  for (int it = 0; it < 64; ++it) {
    float v = xb[(size_t)(cg * 64 + it) * N_ + j];
    vals[it] = v; s1 += v; s2 += v * v;
  }
  red1[cg][j] = s1; red2[cg][j] = s2;
  __syncthreads();
  if (t < 64) {
    float a1 = red1[0][t] + red1[1][t] + red1[2][t] + red1[3][t];
    float a2 = red2[0][t] + red2[1][t] + red2[2][t] + red2[3][t];
    float mu = a1 * (1.f / 256.f);
    float var = a2 * (1.f / 256.f) - mu * mu;
    mu_s[t] = mu;
    r_s[t] = rsqrtf(var + 1e-5f);
  }
  __syncthreads();
  const float mu = mu_s[j], r = r_s[j];
  __hip_bfloat16* xo = xn + (size_t)b * C_ * N_ + n0;
#pragma unroll
  for (int it = 0; it < 64; ++it) {
    const int c = cg * 64 + it;  // wave-uniform c
    float v = (vals[it] - mu) * r * lw[c] + lb[c];
    xo[(size_t)c * N_ + j] = __float2bfloat16(v);
    float s = v;
    s += __shfl_xor(s, 32);
    s += __shfl_xor(s, 16);
    s += __shfl_xor(s, 8);
    s += __shfl_xor(s, 4);
    s += __shfl_xor(s, 2);
    s += __shfl_xor(s, 1);
    if (j == 0) atomicAdd(&xbar[b * C_ + c], s);
  }
}

// Kernel B: per-batch Gram S = xn @ xn^T (256x256, K=9216), bf16 MFMA, fp32 accum.
// Grid = B * 16 tiles (64x64 each), 4 waves -> 32x32 quadrant each, 2x2 of 16x16 MFMA.
__global__ __launch_bounds__(256) void kB_gram(const __hip_bfloat16* __restrict__ xn,
                                               float* __restrict__ S) {
  const int b = blockIdx.x >> 4;
  const int tile = blockIdx.x & 15;
  const int ti = tile >> 2, tj = tile & 3;
  const int t = threadIdx.x, lane = t & 63, w = t >> 6;
  const int rA = ti * 64 + (w >> 1) * 32;
  const int rB = tj * 64 + (w & 1) * 32;
  const int lr = lane & 15, lk = lane >> 4;  // lk in 0..3
  const __hip_bfloat16* Xb = xn + (size_t)b * C_ * N_;
  const __hip_bfloat16* pa = Xb + (size_t)(rA + lr) * N_ + lk * 8;
  const __hip_bfloat16* pb = Xb + (size_t)(rB + lr) * N_ + lk * 8;
  f32x4 acc00 = {0.f,0.f,0.f,0.f}, acc01 = {0.f,0.f,0.f,0.f};
  f32x4 acc10 = {0.f,0.f,0.f,0.f}, acc11 = {0.f,0.f,0.f,0.f};
  for (int k0 = 0; k0 < N_; k0 += 32) {
    short8 a0 = *reinterpret_cast<const short8*>(pa + k0);
    short8 a1 = *reinterpret_cast<const short8*>(pa + (size_t)16 * N_ + k0);
    short8 b0 = *reinterpret_cast<const short8*>(pb + k0);
    short8 b1 = *reinterpret_cast<const short8*>(pb + (size_t)16 * N_ + k0);
    acc00 = __builtin_amdgcn_mfma_f32_16x16x32_bf16(a0, b0, acc00, 0, 0, 0);
    acc01 = __builtin_amdgcn_mfma_f32_16x16x32_bf16(a0, b1, acc01, 0, 0, 0);
    acc10 = __builtin_amdgcn_mfma_f32_16x16x32_bf16(a1, b0, acc10, 0, 0, 0);
    acc11 = __builtin_amdgcn_mfma_f32_16x16x32_bf16(a1, b1, acc11, 0, 0, 0);
  }
  float* Sb = S + (size_t)b * C_ * C_;
  const int orow = lk * 4;
#pragma unroll
  for (int r = 0; r < 4; ++r) {
    Sb[(rA + orow + r) * C_ + rB + lr]           = acc00[r];
    Sb[(rA + orow + r) * C_ + rB + 16 + lr]      = acc01[r];
    Sb[(rA + 16 + orow + r) * C_ + rB + lr]      = acc10[r];
    Sb[(rA + 16 + orow + r) * C_ + rB + 16 + lr] = acc11[r];
  }
}

// Kernel C: per (b, h): logits = scale * Wq_h S Wk_h^T -> softmax -> xabar = attn @ vbar_h
__global__ __launch_bounds__(256) void kC_attn(const float* __restrict__ S,
    const float* __restrict__ w_qkv, const float* __restrict__ xbar,
    float* __restrict__ xabar) {
  __shared__ float buf[32 * 256];   // Wq_h, then reused for temp = Wq_h @ S
  __shared__ float vbar[32];
  __shared__ float att[32 * 33];
  const int t = threadIdx.x;
  const int b = blockIdx.x >> 3, h = blockIdx.x & 7;
  const float* Wq = w_qkv + (size_t)(h * 32) * 256;
  const float* Wk = w_qkv + (size_t)(256 + h * 32) * 256;
  const float* Wv = w_qkv + (size_t)(512 + h * 32) * 256;
  for (int i = t; i < 32 * 256; i += 256) buf[i] = Wq[i];
  if (t < 32) {
    float s = 0.f;
    for (int c = 0; c < 256; ++c) s += Wv[t * 256 + c] * xbar[b * 256 + c];
    vbar[t] = s * (1.f / (float)N_);
  }
  __syncthreads();
  // temp[d][t] = sum_c Wq[d][c] * S[b][c][t]
  float acc[32];
#pragma unroll
  for (int d = 0; d < 32; ++d) acc[d] = 0.f;
  const float* Sb = S + (size_t)b * C_ * C_;
  for (int c = 0; c < 256; ++c) {
    float sv = Sb[c * 256 + t];
#pragma unroll
    for (int d = 0; d < 32; ++d) acc[d] += buf[d * 256 + c] * sv;
  }
  __syncthreads();
#pragma unroll
  for (int d = 0; d < 32; ++d) buf[d * 256 + t] = acc[d];
  __syncthreads();
  // logits[d][e] = scale * sum_c temp[d][c] * Wk[e][c]
  {
    const int d = t >> 3, e0 = (t & 7) * 4;
    float l0 = 0.f, l1 = 0.f, l2 = 0.f, l3 = 0.f;
    for (int c = 0; c < 256; ++c) {
      float tv = buf[d * 256 + c];
      l0 += tv * Wk[(e0 + 0) * 256 + c];
      l1 += tv * Wk[(e0 + 1) * 256 + c];
      l2 += tv * Wk[(e0 + 2) * 256 + c];
      l3 += tv * Wk[(e0 + 3) * 256 + c];
    }
    const float scale = 0.17677669529663687f;  // 1/sqrt(32)
    att[d * 33 + e0 + 0] = l0 * scale;
    att[d * 33 + e0 + 1] = l1 * scale;
    att[d * 33 + e0 + 2] = l2 * scale;
    att[d * 33 + e0 + 3] = l3 * scale;
  }
  __syncthreads();
  if (t < 32) {
    float mx = -1e30f;
    for (int e = 0; e < 32; ++e) mx = fmaxf(mx, att[t * 33 + e]);
    float p[32];
    float sm = 0.f;
#pragma unroll
    for (int e = 0; e < 32; ++e) { p[e] = expf(att[t * 33 + e] - mx); sm += p[e]; }
    float inv = 1.f / sm, xa = 0.f;
#pragma unroll
    for (int e = 0; e < 32; ++e) xa += p[e] * vbar[e];
    xabar[b * 256 + h * 32 + t] = xa * inv;
  }
}

// Kernel D: out[b][o] = sigmoid(w_proj[o,:] . xabar[b,:] + b_proj[o])
__global__ __launch_bounds__(256) void kD_out(const float* __restrict__ xabar,
    const float* __restrict__ w_proj, const float* __restrict__ b_proj,
    float* __restrict__ out) {
  __shared__ float xa[256];
  const int t = threadIdx.x, b = blockIdx.x;
  xa[t] = xabar[b * 256 + t];
  __syncthreads();
  float acc = b_proj[t];
  const float* wp = w_proj + (size_t)t * 256;
  for (int c = 0; c < 256; ++c) acc += wp[c] * xa[c];
  out[b * 256 + t] = 1.f / (1.f + expf(-acc));
}

extern "C" void kernel_launch(void* const* d_in, const int* in_sizes, int n_in,
                              void* d_out, int out_size, void* d_ws, size_t ws_size,
                              hipStream_t stream) {
  const float* x      = (const float*)d_in[0];
  const float* ln_w   = (const float*)d_in[1];
  const float* ln_b   = (const float*)d_in[2];
  const float* w_qkv  = (const float*)d_in[3];
  const float* w_proj = (const float*)d_in[4];
  const float* b_proj = (const float*)d_in[5];
  float* out = (float*)d_out;

  char* ws = (char*)d_ws;
  __hip_bfloat16* xn = (__hip_bfloat16*)ws;             // 16*256*9216*2 = 75,497,472 B
  float* S     = (float*)(ws + 75497472);               // 16*256*256*4  =  4,194,304 B
  float* xbar  = (float*)(ws + 79691776);               // 16*256*4
  float* xabar = (float*)(ws + 79708160);               // 16*256*4

  hipMemsetAsync(xbar, 0, 16384, stream);
  kA_lnorm<<<B_ * NCH, 256, 0, stream>>>(x, ln_w, ln_b, xn, xbar);
  kB_gram<<<B_ * 16, 256, 0, stream>>>(xn, S);
  kC_attn<<<B_ * 8, 256, 0, stream>>>(S, w_qkv, xbar, xabar);
  kD_out<<<B_, 256, 0, stream>>>(xabar, w_proj, b_proj, out);
}

// Round 3
// 525.658 us; speedup vs baseline: 1.0272x; 1.0272x over previous
//
#include <hip/hip_runtime.h>
#include <hip/hip_bf16.h>

#define B_ 16
#define C_ 256
#define N_ 9216

using short8 = __attribute__((ext_vector_type(8))) short;
using f32x4  = __attribute__((ext_vector_type(4))) float;

__device__ __forceinline__ float4 shfl_xor4(float4 v, int m) {
  float4 r;
  r.x = __shfl_xor(v.x, m);
  r.y = __shfl_xor(v.y, m);
  r.z = __shfl_xor(v.z, m);
  r.w = __shfl_xor(v.w, m);
  return r;
}

// byte offset into the [256][128]-bf16 LDS tile, XOR-swizzled within each row
// (row stride 256B; flips byte bits 4-6 -> ds_read_b128 across 16 rows is ~2-way)
#define SWZB(row, bc) (((row) << 8) + ((bc) ^ (((row) & 7) << 4)))

// Fused LayerNorm + Gram: each block handles one batch b and a 256-column chunk
// (two 128-col LDS tiles), accumulating the 256x256 partial Gram into S via atomics,
// and per-channel column-sums into xbar.
__global__ __launch_bounds__(1024, 4) void kAB_ln_gram(
    const float* __restrict__ x, const float* __restrict__ ln_w,
    const float* __restrict__ ln_b, float* __restrict__ S,
    float* __restrict__ xbar) {
  __shared__ char XTraw[65536];           // bf16 tile [256][128]; aliased by stats scratch
  __shared__ float lw_s[256], lb_s[256];
  __shared__ float4 mu_s[32], r_s[32];

  const int t = threadIdx.x;
  const int lane = t & 63;
  const int w = t >> 6;          // wave 0..15
  const int colq = t & 31;       // float4-column 0..31 (covers 128 cols)
  const int cgrp = t >> 5;       // channel group 0..31 (8 channels each)
  const int lr = lane & 15, lk = lane >> 4;
  const int wr = w >> 2, wc = w & 3;

  const int b = blockIdx.x / 36;
  const int chunk = blockIdx.x % 36;
  const int nbase = chunk * 256;

  if (t < 256) { lw_s[t] = ln_w[t]; lb_s[t] = ln_b[t]; }

  f32x4 acc[4][4];
#pragma unroll
  for (int m = 0; m < 4; ++m)
#pragma unroll
    for (int n = 0; n < 4; ++n) acc[m][n] = (f32x4){0.f, 0.f, 0.f, 0.f};
  float xs[8];
#pragma unroll
  for (int i = 0; i < 8; ++i) xs[i] = 0.f;

  float4* sred1 = (float4*)XTraw;            // [16][32]
  float4* sred2 = (float4*)(XTraw + 8192);   // [16][32]

  for (int tt = 0; tt < 2; ++tt) {
    const int n0t = nbase + tt * 128;
    const float* xb = x + (size_t)b * C_ * N_ + n0t + colq * 4;

    // ---- pass A: column stats over all 256 channels ----
    float4 s1 = {0.f, 0.f, 0.f, 0.f}, s2 = {0.f, 0.f, 0.f, 0.f};
#pragma unroll
    for (int i = 0; i < 8; ++i) {
      const int c = cgrp * 8 + i;
      float4 v = *reinterpret_cast<const float4*>(xb + (size_t)c * N_);
      s1.x += v.x; s1.y += v.y; s1.z += v.z; s1.w += v.w;
      s2.x += v.x * v.x; s2.y += v.y * v.y; s2.z += v.z * v.z; s2.w += v.w * v.w;
    }
    s1 += shfl_xor4(s1, 32);
    s2 += shfl_xor4(s2, 32);
    if (lane < 32) { sred1[w * 32 + colq] = s1; sred2[w * 32 + colq] = s2; }
    __syncthreads();
    if (t < 32) {
      float4 a1 = {0.f, 0.f, 0.f, 0.f}, a2 = {0.f, 0.f, 0.f, 0.f};
#pragma unroll
      for (int j = 0; j < 16; ++j) {
        float4 u1 = sred1[j * 32 + t], u2 = sred2[j * 32 + t];
        a1.x += u1.x; a1.y += u1.y; a1.z += u1.z; a1.w += u1.w;
        a2.x += u2.x; a2.y += u2.y; a2.z += u2.z; a2.w += u2.w;
      }
      float4 mu, rv;
      mu.x = a1.x * (1.f / 256.f); mu.y = a1.y * (1.f / 256.f);
      mu.z = a1.z * (1.f / 256.f); mu.w = a1.w * (1.f / 256.f);
      rv.x = rsqrtf(a2.x * (1.f / 256.f) - mu.x * mu.x + 1e-5f);
      rv.y = rsqrtf(a2.y * (1.f / 256.f) - mu.y * mu.y + 1e-5f);
      rv.z = rsqrtf(a2.z * (1.f / 256.f) - mu.z * mu.z + 1e-5f);
      rv.w = rsqrtf(a2.w * (1.f / 256.f) - mu.w * mu.w + 1e-5f);
      mu_s[t] = mu; r_s[t] = rv;
    }
    __syncthreads();

    // ---- pass B: normalize (re-read from cache), write bf16 tile ----
    const float4 mu = mu_s[colq], rv = r_s[colq];
#pragma unroll
    for (int i = 0; i < 8; ++i) {
      const int c = cgrp * 8 + i;
      float4 v = *reinterpret_cast<const float4*>(xb + (size_t)c * N_);
      const float g = lw_s[c], be = lb_s[c];
      float4 xv;
      xv.x = (v.x - mu.x) * rv.x * g + be;
      xv.y = (v.y - mu.y) * rv.y * g + be;
      xv.z = (v.z - mu.z) * rv.z * g + be;
      xv.w = (v.w - mu.w) * rv.w * g + be;
      xs[i] += xv.x + xv.y + xv.z + xv.w;
      __hip_bfloat16 h0 = __float2bfloat16(xv.x);
      __hip_bfloat16 h1 = __float2bfloat16(xv.y);
      __hip_bfloat16 h2 = __float2bfloat16(xv.z);
      __hip_bfloat16 h3 = __float2bfloat16(xv.w);
      ushort4 u;
      u.x = *reinterpret_cast<unsigned short*>(&h0);
      u.y = *reinterpret_cast<unsigned short*>(&h1);
      u.z = *reinterpret_cast<unsigned short*>(&h2);
      u.w = *reinterpret_cast<unsigned short*>(&h3);
      *reinterpret_cast<ushort4*>(XTraw + SWZB(c, colq * 8)) = u;
    }
    __syncthreads();

    // ---- MFMA: Gram partial over this 128-col tile ----
#pragma unroll
    for (int kk = 0; kk < 4; ++kk) {
      short8 af[4], bg[4];
#pragma unroll
      for (int m = 0; m < 4; ++m)
        af[m] = *reinterpret_cast<const short8*>(
            XTraw + SWZB(wr * 64 + m * 16 + lr, kk * 64 + lk * 16));
#pragma unroll
      for (int n = 0; n < 4; ++n)
        bg[n] = *reinterpret_cast<const short8*>(
            XTraw + SWZB(wc * 64 + n * 16 + lr, kk * 64 + lk * 16));
#pragma unroll
      for (int m = 0; m < 4; ++m)
#pragma unroll
        for (int n = 0; n < 4; ++n)
          acc[m][n] = __builtin_amdgcn_mfma_f32_16x16x32_bf16(af[m], bg[n], acc[m][n], 0, 0, 0);
    }
    __syncthreads();
  }

  // ---- epilogue: atomic-accumulate partial Gram into S[b] ----
  float* Sb = S + (size_t)b * 65536;
  const int orow = lk * 4;
#pragma unroll
  for (int m = 0; m < 4; ++m)
#pragma unroll
    for (int n = 0; n < 4; ++n) {
      const int row = wr * 64 + m * 16 + orow;
      const int col = wc * 64 + n * 16 + lr;
#pragma unroll
      for (int r = 0; r < 4; ++r)
        atomicAdd(&Sb[(row + r) * 256 + col], acc[m][n][r]);
    }

  // ---- xbar: reduce per-channel column sums over colq, one atomic per channel ----
#pragma unroll
  for (int i = 0; i < 8; ++i) {
    float s = xs[i];
    s += __shfl_xor(s, 1);
    s += __shfl_xor(s, 2);
    s += __shfl_xor(s, 4);
    s += __shfl_xor(s, 8);
    s += __shfl_xor(s, 16);
    if ((lane & 31) == 0) atomicAdd(&xbar[b * 256 + cgrp * 8 + i], s);
  }
}

// Kernel C: per (b, h): logits = scale * Wq_h S Wk_h^T -> softmax -> xabar = attn @ vbar_h
__global__ __launch_bounds__(256) void kC_attn(const float* __restrict__ S,
    const float* __restrict__ w_qkv, const float* __restrict__ xbar,
    float* __restrict__ xabar) {
  __shared__ float buf[32 * 257];   // Wq_h, then temp = Wq_h @ S (stride 257: bank-safe)
  __shared__ float wk_s[32 * 257];
  __shared__ float vbar[32];
  __shared__ float att[32 * 33];
  const int t = threadIdx.x;
  const int b = blockIdx.x >> 3, h = blockIdx.x & 7;
  const float* Wq = w_qkv + (size_t)(h * 32) * 256;
  const float* Wk = w_qkv + (size_t)(256 + h * 32) * 256;
  const float* Wv = w_qkv + (size_t)(512 + h * 32) * 256;
  for (int i = t; i < 8192; i += 256) {
    const int r = i >> 8, c = i & 255;
    buf[r * 257 + c] = Wq[i];
    wk_s[r * 257 + c] = Wk[i];
  }
  if (t < 32) {
    float s = 0.f;
    for (int c = 0; c < 256; ++c) s += Wv[t * 256 + c] * xbar[b * 256 + c];
    vbar[t] = s * (1.f / (float)N_);
  }
  __syncthreads();
  // temp[d][t] = sum_c Wq[d][c] * S[b][c][t]
  float acc[32];
#pragma unroll
  for (int d = 0; d < 32; ++d) acc[d] = 0.f;
  const float* Sb = S + (size_t)b * 65536;
  for (int c = 0; c < 256; ++c) {
    float sv = Sb[c * 256 + t];
#pragma unroll
    for (int d = 0; d < 32; ++d) acc[d] += buf[d * 257 + c] * sv;
  }
  __syncthreads();
#pragma unroll
  for (int d = 0; d < 32; ++d) buf[d * 257 + t] = acc[d];
  __syncthreads();
  // logits[d][e] = scale * sum_c temp[d][c] * Wk[e][c]
  {
    const int d = t >> 3, e0 = (t & 7) * 4;
    float l0 = 0.f, l1 = 0.f, l2 = 0.f, l3 = 0.f;
    for (int c = 0; c < 256; ++c) {
      const float tv = buf[d * 257 + c];
      l0 += tv * wk_s[(e0 + 0) * 257 + c];
      l1 += tv * wk_s[(e0 + 1) * 257 + c];
      l2 += tv * wk_s[(e0 + 2) * 257 + c];
      l3 += tv * wk_s[(e0 + 3) * 257 + c];
    }
    const float scale = 0.17677669529663687f;  // 1/sqrt(32)
    att[d * 33 + e0 + 0] = l0 * scale;
    att[d * 33 + e0 + 1] = l1 * scale;
    att[d * 33 + e0 + 2] = l2 * scale;
    att[d * 33 + e0 + 3] = l3 * scale;
  }
  __syncthreads();
  if (t < 32) {
    float mx = -1e30f;
    for (int e = 0; e < 32; ++e) mx = fmaxf(mx, att[t * 33 + e]);
    float p[32];
    float sm = 0.f;
#pragma unroll
    for (int e = 0; e < 32; ++e) { p[e] = expf(att[t * 33 + e] - mx); sm += p[e]; }
    float inv = 1.f / sm, xa = 0.f;
#pragma unroll
    for (int e = 0; e < 32; ++e) xa += p[e] * vbar[e];
    xabar[b * 256 + h * 32 + t] = xa * inv;
  }
}

// Kernel D: out[b][o] = sigmoid(w_proj[o,:] . xabar[b,:] + b_proj[o])
__global__ __launch_bounds__(256) void kD_out(const float* __restrict__ xabar,
    const float* __restrict__ w_proj, const float* __restrict__ b_proj,
    float* __restrict__ out) {
  __shared__ float xa[256];
  const int t = threadIdx.x, b = blockIdx.x;
  xa[t] = xabar[b * 256 + t];
  __syncthreads();
  float acc = b_proj[t];
  const float4* wp = reinterpret_cast<const float4*>(w_proj + (size_t)t * 256);
  const float4* xav = reinterpret_cast<const float4*>(xa);
#pragma unroll 4
  for (int c = 0; c < 64; ++c) {
    float4 wv = wp[c], xv = xav[c];
    acc += wv.x * xv.x + wv.y * xv.y + wv.z * xv.z + wv.w * xv.w;
  }
  out[b * 256 + t] = 1.f / (1.f + expf(-acc));
}

extern "C" void kernel_launch(void* const* d_in, const int* in_sizes, int n_in,
                              void* d_out, int out_size, void* d_ws, size_t ws_size,
                              hipStream_t stream) {
  const float* x      = (const float*)d_in[0];
  const float* ln_w   = (const float*)d_in[1];
  const float* ln_b   = (const float*)d_in[2];
  const float* w_qkv  = (const float*)d_in[3];
  const float* w_proj = (const float*)d_in[4];
  const float* b_proj = (const float*)d_in[5];
  float* out = (float*)d_out;

  char* ws = (char*)d_ws;
  float* S     = (float*)ws;                     // 16*256*256*4 = 4,194,304 B
  float* xbar  = (float*)(ws + 4194304);         // 16*256*4 = 16 KB
  float* xabar = (float*)(ws + 4210688);         // 16*256*4 = 16 KB

  hipMemsetAsync(ws, 0, 4194304 + 32768, stream);
  kAB_ln_gram<<<16 * 36, 1024, 0, stream>>>(x, ln_w, ln_b, S, xbar);
  kC_attn<<<B_ * 8, 256, 0, stream>>>(S, w_qkv, xbar, xabar);
  kD_out<<<B_, 256, 0, stream>>>(xabar, w_proj, b_proj, out);
}

// Round 4
// 415.204 us; speedup vs baseline: 1.3005x; 1.2660x over previous
//
#include <hip/hip_runtime.h>
#include <hip/hip_bf16.h>

#define B_ 16
#define NTOT 9216

using short8 = __attribute__((ext_vector_type(8))) short;
using f32x4  = __attribute__((ext_vector_type(4))) float;

__device__ __forceinline__ unsigned short bf16u(float f) {
  __hip_bfloat16 h = __float2bfloat16(f);
  return *reinterpret_cast<unsigned short*>(&h);
}
__device__ __forceinline__ float bf16f(short u) {
  unsigned int x = ((unsigned int)(unsigned short)u) << 16;
  return __uint_as_float(x);
}
__device__ __forceinline__ float4 shfl_xor4(float4 v, int m) {
  float4 r;
  r.x = __shfl_xor(v.x, m); r.y = __shfl_xor(v.y, m);
  r.z = __shfl_xor(v.z, m); r.w = __shfl_xor(v.w, m);
  return r;
}

// LDS byte offsets (all swizzled: XOR byte bits 4-6 with row&7)
#define XTB(n, cb) (((n) << 9) + ((cb) ^ (((n) & 7) << 4)))            // Xt [64 n][256 ch] bf16
#define QB(r, cb)  (32768 + ((r) << 7) + ((cb) ^ (((r) & 7) << 4)))    // Q  [256 r][64 n] bf16
#define KB(r, cb)  (((r) << 7) + ((cb) ^ (((r) & 7) << 4)))            // K aliases Xt region

__global__ void kPrep(const float* __restrict__ w_qkv, unsigned short* __restrict__ wqkb) {
  const int i = blockIdx.x * 256 + threadIdx.x;     // 32768 threads x 4 elems = 131072 (Wq+Wk)
  float4 v = *reinterpret_cast<const float4*>(w_qkv + (size_t)i * 4);
  ushort4 u;
  u.x = bf16u(v.x); u.y = bf16u(v.y); u.z = bf16u(v.z); u.w = bf16u(v.w);
  *reinterpret_cast<ushort4*>(wqkb + (size_t)i * 4) = u;
}

// Fused: LN (stats + normalize, x read once) -> Q/K projection (MFMA, bf16 weights)
// -> per-head logits accumulated in registers across chunks -> one atomic flush.
__global__ __launch_bounds__(512, 4) void kMain(
    const float* __restrict__ x, const float* __restrict__ ln_w,
    const float* __restrict__ ln_b, const __hip_bfloat16* __restrict__ wqkb,
    float* __restrict__ logits, float* __restrict__ xbar) {
  __shared__ char lds[65536];                 // [0,32K): Xt then K ; [32K,64K): Q
  __shared__ float4 sred1[8][16], sred2[8][16];
  __shared__ float muv[64], rcv[64], lw_s[256], lb_s[256];

  const int t = threadIdx.x, lane = t & 63, w = t >> 6;
  const int colq = t & 15, cgrp = t >> 4;
  const int lr = lane & 15, lk = lane >> 4;
  const int b = blockIdx.x >> 5, j = blockIdx.x & 31;
  const int ch0 = (j * 144) >> 5, ch1 = ((j + 1) * 144) >> 5;

  if (t < 256) { lw_s[t] = ln_w[t]; lb_s[t] = ln_b[t]; }

  f32x4 lacc[2][2];
#pragma unroll
  for (int m = 0; m < 2; ++m)
#pragma unroll
    for (int n = 0; n < 2; ++n) lacc[m][n] = (f32x4){0.f, 0.f, 0.f, 0.f};

  const __hip_bfloat16* wq = wqkb;
  const __hip_bfloat16* wk = wqkb + 65536;

  for (int ch = ch0; ch < ch1; ++ch) {
    const int n0 = ch * 64;
    __syncthreads();   // protect Xt/K and Q regions from previous chunk's readers

    // ---- P0: read x fp32 once, col-stats, stage raw bf16 transposed ----
    const float* xp = x + (size_t)b * 256 * NTOT + n0 + colq * 4;
    float4 v[8];
    float4 s1 = {0.f,0.f,0.f,0.f}, s2 = {0.f,0.f,0.f,0.f};
#pragma unroll
    for (int i = 0; i < 8; ++i)
      v[i] = *reinterpret_cast<const float4*>(xp + (size_t)(cgrp * 8 + i) * NTOT);
#pragma unroll
    for (int i = 0; i < 8; ++i) {
      s1.x += v[i].x; s1.y += v[i].y; s1.z += v[i].z; s1.w += v[i].w;
      s2.x += v[i].x*v[i].x; s2.y += v[i].y*v[i].y;
      s2.z += v[i].z*v[i].z; s2.w += v[i].w*v[i].w;
    }
    {
      short8 p0, p1, p2, p3;
#pragma unroll
      for (int i = 0; i < 8; ++i) {
        p0[i] = (short)bf16u(v[i].x);
        p1[i] = (short)bf16u(v[i].y);
        p2[i] = (short)bf16u(v[i].z);
        p3[i] = (short)bf16u(v[i].w);
      }
      *reinterpret_cast<short8*>(lds + XTB(colq*4+0, cgrp*16)) = p0;
      *reinterpret_cast<short8*>(lds + XTB(colq*4+1, cgrp*16)) = p1;
      *reinterpret_cast<short8*>(lds + XTB(colq*4+2, cgrp*16)) = p2;
      *reinterpret_cast<short8*>(lds + XTB(colq*4+3, cgrp*16)) = p3;
    }
    s1 += shfl_xor4(s1, 16); s1 += shfl_xor4(s1, 32);
    s2 += shfl_xor4(s2, 16); s2 += shfl_xor4(s2, 32);
    if (lane < 16) { sred1[w][lane] = s1; sred2[w][lane] = s2; }
    __syncthreads();
    if (t < 16) {
      float4 a1 = {0.f,0.f,0.f,0.f}, a2 = {0.f,0.f,0.f,0.f};
#pragma unroll
      for (int ww = 0; ww < 8; ++ww) {
        float4 u1 = sred1[ww][t], u2 = sred2[ww][t];
        a1.x += u1.x; a1.y += u1.y; a1.z += u1.z; a1.w += u1.w;
        a2.x += u2.x; a2.y += u2.y; a2.z += u2.z; a2.w += u2.w;
      }
      const float inv = 1.f / 256.f;
      float mx_ = a1.x*inv, my_ = a1.y*inv, mz_ = a1.z*inv, mw_ = a1.w*inv;
      muv[t*4+0] = mx_; muv[t*4+1] = my_; muv[t*4+2] = mz_; muv[t*4+3] = mw_;
      rcv[t*4+0] = rsqrtf(a2.x*inv - mx_*mx_ + 1e-5f);
      rcv[t*4+1] = rsqrtf(a2.y*inv - my_*my_ + 1e-5f);
      rcv[t*4+2] = rsqrtf(a2.z*inv - mz_*mz_ + 1e-5f);
      rcv[t*4+3] = rsqrtf(a2.w*inv - mw_*mw_ + 1e-5f);
    }
    __syncthreads();

    // ---- P1: normalize in LDS, per-channel column-sum -> xbar atomics ----
    float xsum[8];
#pragma unroll
    for (int i = 0; i < 8; ++i) xsum[i] = 0.f;
#pragma unroll
    for (int jc = 0; jc < 4; ++jc) {
      const int row = colq * 4 + jc;
      short8 raw = *reinterpret_cast<short8*>(lds + XTB(row, cgrp*16));
      const float mu = muv[row], rc = rcv[row];
      short8 o;
#pragma unroll
      for (int i = 0; i < 8; ++i) {
        float xn = (bf16f(raw[i]) - mu) * rc * lw_s[cgrp*8+i] + lb_s[cgrp*8+i];
        xsum[i] += xn;
        o[i] = (short)bf16u(xn);
      }
      *reinterpret_cast<short8*>(lds + XTB(row, cgrp*16)) = o;
    }
#pragma unroll
    for (int i = 0; i < 8; ++i) {
      float s = xsum[i];
      s += __shfl_xor(s, 1); s += __shfl_xor(s, 2);
      s += __shfl_xor(s, 4); s += __shfl_xor(s, 8);
      if ((lane & 15) == 0) atomicAdd(&xbar[b*256 + cgrp*8 + i], s);
    }
    __syncthreads();

    // ---- P2a: Q = Wq . Xn  (A.B^T with B-rows = Xt rows) ----
    f32x4 pa[2][4];
#pragma unroll
    for (int m = 0; m < 2; ++m)
#pragma unroll
      for (int n = 0; n < 4; ++n) pa[m][n] = (f32x4){0.f,0.f,0.f,0.f};
    const __hip_bfloat16* wqp = wq + (size_t)(w*32 + lr) * 256 + lk * 8;
#pragma unroll
    for (int kk = 0; kk < 8; ++kk) {
      short8 a0 = *reinterpret_cast<const short8*>(wqp + kk*32);
      short8 a1 = *reinterpret_cast<const short8*>(wqp + 16*256 + kk*32);
      short8 bx[4];
#pragma unroll
      for (int n = 0; n < 4; ++n)
        bx[n] = *reinterpret_cast<short8*>(lds + XTB(n*16 + lr, (kk*32 + lk*8)*2));
#pragma unroll
      for (int n = 0; n < 4; ++n) {
        pa[0][n] = __builtin_amdgcn_mfma_f32_16x16x32_bf16(a0, bx[n], pa[0][n], 0, 0, 0);
        pa[1][n] = __builtin_amdgcn_mfma_f32_16x16x32_bf16(a1, bx[n], pa[1][n], 0, 0, 0);
      }
    }
    // write Q to its (disjoint) LDS region now; frees regs before K-proj
#pragma unroll
    for (int m = 0; m < 2; ++m)
#pragma unroll
      for (int n = 0; n < 4; ++n)
#pragma unroll
        for (int r = 0; r < 4; ++r)
          *reinterpret_cast<unsigned short*>(lds + QB(w*32 + m*16 + lk*4 + r, (n*16 + lr)*2))
              = bf16u(pa[m][n][r]);

    // ---- P2b: K = Wk . Xn ----
#pragma unroll
    for (int m = 0; m < 2; ++m)
#pragma unroll
      for (int n = 0; n < 4; ++n) pa[m][n] = (f32x4){0.f,0.f,0.f,0.f};
    const __hip_bfloat16* wkp = wk + (size_t)(w*32 + lr) * 256 + lk * 8;
#pragma unroll
    for (int kk = 0; kk < 8; ++kk) {
      short8 a0 = *reinterpret_cast<const short8*>(wkp + kk*32);
      short8 a1 = *reinterpret_cast<const short8*>(wkp + 16*256 + kk*32);
      short8 bx[4];
#pragma unroll
      for (int n = 0; n < 4; ++n)
        bx[n] = *reinterpret_cast<short8*>(lds + XTB(n*16 + lr, (kk*32 + lk*8)*2));
#pragma unroll
      for (int n = 0; n < 4; ++n) {
        pa[0][n] = __builtin_amdgcn_mfma_f32_16x16x32_bf16(a0, bx[n], pa[0][n], 0, 0, 0);
        pa[1][n] = __builtin_amdgcn_mfma_f32_16x16x32_bf16(a1, bx[n], pa[1][n], 0, 0, 0);
      }
    }
    __syncthreads();   // everyone done reading Xt
    // write K over the Xt region
#pragma unroll
    for (int m = 0; m < 2; ++m)
#pragma unroll
      for (int n = 0; n < 4; ++n)
#pragma unroll
        for (int r = 0; r < 4; ++r)
          *reinterpret_cast<unsigned short*>(lds + KB(w*32 + m*16 + lk*4 + r, (n*16 + lr)*2))
              = bf16u(pa[m][n][r]);
    __syncthreads();

    // ---- P4: logits_h += Q_h . K_h^T  (wave = head) ----
#pragma unroll
    for (int kk = 0; kk < 2; ++kk) {
      short8 qa0 = *reinterpret_cast<short8*>(lds + QB(w*32 + lr,      (kk*32 + lk*8)*2));
      short8 qa1 = *reinterpret_cast<short8*>(lds + QB(w*32 + 16 + lr, (kk*32 + lk*8)*2));
      short8 kb0 = *reinterpret_cast<short8*>(lds + KB(w*32 + lr,      (kk*32 + lk*8)*2));
      short8 kb1 = *reinterpret_cast<short8*>(lds + KB(w*32 + 16 + lr, (kk*32 + lk*8)*2));
      lacc[0][0] = __builtin_amdgcn_mfma_f32_16x16x32_bf16(qa0, kb0, lacc[0][0], 0, 0, 0);
      lacc[0][1] = __builtin_amdgcn_mfma_f32_16x16x32_bf16(qa0, kb1, lacc[0][1], 0, 0, 0);
      lacc[1][0] = __builtin_amdgcn_mfma_f32_16x16x32_bf16(qa1, kb0, lacc[1][0], 0, 0, 0);
      lacc[1][1] = __builtin_amdgcn_mfma_f32_16x16x32_bf16(qa1, kb1, lacc[1][1], 0, 0, 0);
    }
  }

  // ---- flush logits: one atomic set per block ----
  float* lg = logits + ((size_t)b * 8 + w) * 1024;
#pragma unroll
  for (int m = 0; m < 2; ++m)
#pragma unroll
    for (int n = 0; n < 2; ++n)
#pragma unroll
      for (int r = 0; r < 4; ++r)
        atomicAdd(&lg[(m*16 + lk*4 + r) * 32 + n*16 + lr], lacc[m][n][r]);
}

// Epilogue: softmax(scale*logits) -> xabar via vbar -> proj -> sigmoid
__global__ __launch_bounds__(256) void kE(const float* __restrict__ logits,
    const float* __restrict__ xbar, const float* __restrict__ w_qkv,
    const float* __restrict__ w_proj, const float* __restrict__ b_proj,
    float* __restrict__ out) {
  __shared__ float xnb[256], vb[256], xa[256];
  __shared__ float stg[256 * 65];
  const int t = threadIdx.x, b = blockIdx.x;
  xnb[t] = xbar[b * 256 + t] * (1.f / (float)NTOT);
  __syncthreads();
  // vbar[t] = Wv[t,:] . xnbar  (Wv staged to LDS in 64-col chunks, coalesced)
  float av = 0.f;
  const float* Wv = w_qkv + 512 * 256;
  for (int c0 = 0; c0 < 256; c0 += 64) {
#pragma unroll
    for (int rr = 0; rr < 16; ++rr) {
      const int row = rr * 16 + (t >> 4);
      const int col = (t & 15) * 4;
      float4 w4 = *reinterpret_cast<const float4*>(Wv + (size_t)row * 256 + c0 + col);
      stg[row*65 + col+0] = w4.x; stg[row*65 + col+1] = w4.y;
      stg[row*65 + col+2] = w4.z; stg[row*65 + col+3] = w4.w;
    }
    __syncthreads();
#pragma unroll 8
    for (int cc = 0; cc < 64; ++cc) av += stg[t*65 + cc] * xnb[c0 + cc];
    __syncthreads();
  }
  vb[t] = av;
  // softmax over e for (h,d) = t
  const float* lg = logits + ((size_t)b * 256 + t) * 32;
  float l[32];
  float mx = -1e30f;
#pragma unroll
  for (int e = 0; e < 32; ++e) { l[e] = lg[e] * 0.17677669529663687f; mx = fmaxf(mx, l[e]); }
  float sm = 0.f;
#pragma unroll
  for (int e = 0; e < 32; ++e) { l[e] = expf(l[e] - mx); sm += l[e]; }
  __syncthreads();   // vb ready
  const int h = t >> 5;
  float acc = 0.f;
#pragma unroll
  for (int e = 0; e < 32; ++e) acc += l[e] * vb[h * 32 + e];
  xa[t] = acc / sm;
  __syncthreads();
  // out[t] = sigmoid(b_proj + w_proj[t,:] . xa)
  float ao = b_proj[t];
  for (int c0 = 0; c0 < 256; c0 += 64) {
#pragma unroll
    for (int rr = 0; rr < 16; ++rr) {
      const int row = rr * 16 + (t >> 4);
      const int col = (t & 15) * 4;
      float4 w4 = *reinterpret_cast<const float4*>(w_proj + (size_t)row * 256 + c0 + col);
      stg[row*65 + col+0] = w4.x; stg[row*65 + col+1] = w4.y;
      stg[row*65 + col+2] = w4.z; stg[row*65 + col+3] = w4.w;
    }
    __syncthreads();
#pragma unroll 8
    for (int cc = 0; cc < 64; ++cc) ao += stg[t*65 + cc] * xa[c0 + cc];
    __syncthreads();
  }
  out[b * 256 + t] = 1.f / (1.f + expf(-ao));
}

extern "C" void kernel_launch(void* const* d_in, const int* in_sizes, int n_in,
                              void* d_out, int out_size, void* d_ws, size_t ws_size,
                              hipStream_t stream) {
  const float* x      = (const float*)d_in[0];
  const float* ln_w   = (const float*)d_in[1];
  const float* ln_b   = (const float*)d_in[2];
  const float* w_qkv  = (const float*)d_in[3];
  const float* w_proj = (const float*)d_in[4];
  const float* b_proj = (const float*)d_in[5];
  float* out = (float*)d_out;

  char* ws = (char*)d_ws;
  unsigned short* wqkb = (unsigned short*)ws;        // 2*256*256*2 = 262144 B
  float* logits = (float*)(ws + 262144);             // 16*8*32*32*4 = 524288 B
  float* xbar   = (float*)(ws + 786432);             // 16*256*4 = 16384 B

  hipMemsetAsync(ws + 262144, 0, 524288 + 16384, stream);
  kPrep<<<128, 256, 0, stream>>>(w_qkv, wqkb);
  kMain<<<512, 512, 0, stream>>>(x, ln_w, ln_b, (const __hip_bfloat16*)wqkb, logits, xbar);
  kE<<<B_, 256, 0, stream>>>(logits, xbar, w_qkv, w_proj, b_proj, out);
}

// Round 5
// 312.926 us; speedup vs baseline: 1.7256x; 1.3268x over previous
//
#include <hip/hip_runtime.h>
#include <hip/hip_bf16.h>

#define NTOT 9216

using short8 = __attribute__((ext_vector_type(8))) short;
using f32x16 = __attribute__((ext_vector_type(16))) float;

__device__ __forceinline__ unsigned short bf16u(float f) {
  __hip_bfloat16 h = __float2bfloat16(f);
  return *reinterpret_cast<unsigned short*>(&h);
}
__device__ __forceinline__ float bf16f(unsigned short u) {
  unsigned int x = ((unsigned int)u) << 16;
  return __uint_as_float(x);
}
__device__ __forceinline__ float4 shfl_xor4(float4 v, int m) {
  float4 r;
  r.x = __shfl_xor(v.x, m); r.y = __shfl_xor(v.y, m);
  r.z = __shfl_xor(v.z, m); r.w = __shfl_xor(v.w, m);
  return r;
}

// LDS tile: [256 ch rows][64 n cols] bf16, row stride 144 B (16B pad: row shift
// = 36 banks = 4 mod 32 -> 32 consecutive rows spread over 8 slot groups, ~4-way max)
#define TB(buf, r, byte) ((buf) * 36992 + (r) * 144 + (byte))

// Fused LN + partial Gram. 16 blocks per batch, 9 chunks of 64 cols each.
// Writes per-block Gram partial (256x256 f32) and xbar partial (256 f32). No atomics.
__global__ __launch_bounds__(1024) void kG(
    const float* __restrict__ x, const float* __restrict__ ln_w,
    const float* __restrict__ ln_b, float* __restrict__ Spart,
    float* __restrict__ xbarp) {
  __shared__ char tile[2 * 36992];
  __shared__ float4 sred1[256], sred2[256];
  __shared__ float muv[64], rcv[64], lw_s[256], lb_s[256], xbp_s[256];

  const int t = threadIdx.x, lane = t & 63, w = t >> 6;
  const int colq = t & 15, rowg = t >> 4;
  const int l31 = lane & 31, hi = lane >> 5;
  const int wr = w >> 2, wc = w & 3;
  const int b = blockIdx.x >> 4, p = blockIdx.x & 15;
  const float* xb = x + (size_t)b * 256 * NTOT;

  if (t < 256) { lw_s[t] = ln_w[t]; lb_s[t] = ln_b[t]; xbp_s[t] = 0.f; }

  f32x16 acc[2][2];
#pragma unroll
  for (int m = 0; m < 2; ++m)
#pragma unroll
    for (int n = 0; n < 2; ++n)
#pragma unroll
      for (int r = 0; r < 16; ++r) acc[m][n][r] = 0.f;

  int n0 = p * 9 * 64;
  float4 vreg[4];
#pragma unroll
  for (int j = 0; j < 4; ++j)
    vreg[j] = *reinterpret_cast<const float4*>(xb + (size_t)(rowg + 64 * j) * NTOT + n0 + colq * 4);

  for (int i = 0; i < 9; ++i) {
    const int buf = i & 1;
    // ---- stage bf16 raw + stats partials from regs ----
    float4 s1 = {0.f, 0.f, 0.f, 0.f}, s2 = {0.f, 0.f, 0.f, 0.f};
#pragma unroll
    for (int j = 0; j < 4; ++j) {
      const float4 v = vreg[j];
      const int r = rowg + 64 * j;
      ushort4 u;
      u.x = bf16u(v.x); u.y = bf16u(v.y); u.z = bf16u(v.z); u.w = bf16u(v.w);
      *reinterpret_cast<ushort4*>(tile + TB(buf, r, colq * 8)) = u;
      s1.x += v.x; s1.y += v.y; s1.z += v.z; s1.w += v.w;
      s2.x += v.x * v.x; s2.y += v.y * v.y; s2.z += v.z * v.z; s2.w += v.w * v.w;
    }
    // ---- issue next chunk's loads (fly under stats/normalize/MFMA) ----
    if (i < 8) {
      const int n1 = n0 + 64;
#pragma unroll
      for (int j = 0; j < 4; ++j)
        vreg[j] = *reinterpret_cast<const float4*>(xb + (size_t)(rowg + 64 * j) * NTOT + n1 + colq * 4);
    }
    // ---- stats reduce ----
    s1 += shfl_xor4(s1, 16); s1 += shfl_xor4(s1, 32);
    s2 += shfl_xor4(s2, 16); s2 += shfl_xor4(s2, 32);
    if (lane < 16) { sred1[w * 16 + colq] = s1; sred2[w * 16 + colq] = s2; }
    __syncthreads();
    if (t < 64) {
      const int cq = t & 15, qq = t >> 4;
      float4 a1 = {0.f, 0.f, 0.f, 0.f}, a2 = {0.f, 0.f, 0.f, 0.f};
#pragma unroll
      for (int u2 = 0; u2 < 4; ++u2) {
        float4 u1v = sred1[(qq * 4 + u2) * 16 + cq], u2v = sred2[(qq * 4 + u2) * 16 + cq];
        a1.x += u1v.x; a1.y += u1v.y; a1.z += u1v.z; a1.w += u1v.w;
        a2.x += u2v.x; a2.y += u2v.y; a2.z += u2v.z; a2.w += u2v.w;
      }
      a1 += shfl_xor4(a1, 16); a1 += shfl_xor4(a1, 32);
      a2 += shfl_xor4(a2, 16); a2 += shfl_xor4(a2, 32);
      if (t < 16) {
        const float inv = 1.f / 256.f;
        float m0 = a1.x * inv, m1 = a1.y * inv, m2 = a1.z * inv, m3 = a1.w * inv;
        muv[cq * 4 + 0] = m0; muv[cq * 4 + 1] = m1;
        muv[cq * 4 + 2] = m2; muv[cq * 4 + 3] = m3;
        rcv[cq * 4 + 0] = rsqrtf(a2.x * inv - m0 * m0 + 1e-5f);
        rcv[cq * 4 + 1] = rsqrtf(a2.y * inv - m1 * m1 + 1e-5f);
        rcv[cq * 4 + 2] = rsqrtf(a2.z * inv - m2 * m2 + 1e-5f);
        rcv[cq * 4 + 3] = rsqrtf(a2.w * inv - m3 * m3 + 1e-5f);
      }
    }
    __syncthreads();
    // ---- normalize tile in place + xbar partial ----
    const float mu0 = muv[colq * 4 + 0], mu1 = muv[colq * 4 + 1];
    const float mu2 = muv[colq * 4 + 2], mu3 = muv[colq * 4 + 3];
    const float rc0 = rcv[colq * 4 + 0], rc1 = rcv[colq * 4 + 1];
    const float rc2 = rcv[colq * 4 + 2], rc3 = rcv[colq * 4 + 3];
#pragma unroll
    for (int j = 0; j < 4; ++j) {
      const int r = rowg + 64 * j;
      ushort4 u = *reinterpret_cast<ushort4*>(tile + TB(buf, r, colq * 8));
      const float g = lw_s[r], bb = lb_s[r];
      float f0 = (bf16f(u.x) - mu0) * rc0 * g + bb;
      float f1 = (bf16f(u.y) - mu1) * rc1 * g + bb;
      float f2 = (bf16f(u.z) - mu2) * rc2 * g + bb;
      float f3 = (bf16f(u.w) - mu3) * rc3 * g + bb;
      ushort4 o;
      o.x = bf16u(f0); o.y = bf16u(f1); o.z = bf16u(f2); o.w = bf16u(f3);
      *reinterpret_cast<ushort4*>(tile + TB(buf, r, colq * 8)) = o;
      float rs = f0 + f1 + f2 + f3;
      rs += __shfl_xor(rs, 1); rs += __shfl_xor(rs, 2);
      rs += __shfl_xor(rs, 4); rs += __shfl_xor(rs, 8);
      if ((lane & 15) == 0) xbp_s[r] += rs;
    }
    __syncthreads();
    // ---- partial Gram: 16 waves x 64x64, mfma 32x32x16 ----
#pragma unroll
    for (int kk = 0; kk < 4; ++kk) {
      short8 a0 = *reinterpret_cast<short8*>(tile + TB(buf, wr * 64 + l31,      kk * 32 + hi * 16));
      short8 a1 = *reinterpret_cast<short8*>(tile + TB(buf, wr * 64 + 32 + l31, kk * 32 + hi * 16));
      short8 b0 = *reinterpret_cast<short8*>(tile + TB(buf, wc * 64 + l31,      kk * 32 + hi * 16));
      short8 b1 = *reinterpret_cast<short8*>(tile + TB(buf, wc * 64 + 32 + l31, kk * 32 + hi * 16));
      acc[0][0] = __builtin_amdgcn_mfma_f32_32x32x16_bf16(a0, b0, acc[0][0], 0, 0, 0);
      acc[0][1] = __builtin_amdgcn_mfma_f32_32x32x16_bf16(a0, b1, acc[0][1], 0, 0, 0);
      acc[1][0] = __builtin_amdgcn_mfma_f32_32x32x16_bf16(a1, b0, acc[1][0], 0, 0, 0);
      acc[1][1] = __builtin_amdgcn_mfma_f32_32x32x16_bf16(a1, b1, acc[1][1], 0, 0, 0);
    }
    n0 += 64;
  }

  // ---- flush partials (plain stores, no atomics) ----
  float* Sp = Spart + (size_t)blockIdx.x * 65536;
#pragma unroll
  for (int m = 0; m < 2; ++m)
#pragma unroll
    for (int n = 0; n < 2; ++n)
#pragma unroll
      for (int r = 0; r < 16; ++r) {
        const int row = wr * 64 + m * 32 + (r & 3) + 8 * (r >> 2) + 4 * hi;
        const int col = wc * 64 + n * 32 + l31;
        Sp[row * 256 + col] = acc[m][n][r];
      }
  if (t < 256) xbarp[blockIdx.x * 256 + t] = xbp_s[t];
}

// Reduce 16 partials per batch -> S[b] (streaming, partials mostly L3-resident)
__global__ __launch_bounds__(256) void kR(const float4* __restrict__ Spart,
                                          float4* __restrict__ S) {
  const int idx = blockIdx.x * 256 + threadIdx.x;   // float4 index, 262144 total
  const int b = idx >> 14, o = idx & 16383;
  float4 a = {0.f, 0.f, 0.f, 0.f};
#pragma unroll
  for (int p = 0; p < 16; ++p) {
    float4 v = Spart[(size_t)(b * 16 + p) * 16384 + o];
    a.x += v.x; a.y += v.y; a.z += v.z; a.w += v.w;
  }
  S[(size_t)b * 16384 + o] = a;
}

// Per (b,h): T = Wq_h.S ; logits = scale*T.Wk_h^T ; softmax ; vbar = Wv_h.xnbar ;
// xabar = attn.vbar
__global__ __launch_bounds__(256) void kC2(const float* __restrict__ S,
    const float* __restrict__ w_qkv, const float* __restrict__ xbarp,
    float* __restrict__ xabar) {
  __shared__ float wq_s[32 * 257];   // then reused as T
  __shared__ float wk_s[32 * 257];
  __shared__ float att[32 * 33];
  __shared__ float xnb[256], vbp[256], vbar[32];
  const int t = threadIdx.x;
  const int b = blockIdx.x >> 3, h = blockIdx.x & 7;
  const float* Wq = w_qkv + (size_t)(h * 32) * 256;
  const float* Wk = w_qkv + (size_t)(256 + h * 32) * 256;
  const float* Wv = w_qkv + (size_t)(512 + h * 32) * 256;
  for (int i = t; i < 8192; i += 256) {
    const int r = i >> 8, c = i & 255;
    wq_s[r * 257 + c] = Wq[i];
    wk_s[r * 257 + c] = Wk[i];
  }
  {
    float s = 0.f;
#pragma unroll
    for (int p = 0; p < 16; ++p) s += xbarp[(b * 16 + p) * 256 + t];
    xnb[t] = s * (1.f / (float)NTOT);
  }
  __syncthreads();
  // vbar partials: e = t&31, segment of 32 channels per 32-thread group
  {
    const int e = t & 31, seg = t >> 5;
    float s = 0.f;
#pragma unroll
    for (int cc = 0; cc < 32; ++cc)
      s += Wv[e * 256 + seg * 32 + cc] * xnb[seg * 32 + cc];
    vbp[seg * 32 + e] = s;
  }
  __syncthreads();
  if (t < 32) {
    float s = 0.f;
#pragma unroll
    for (int seg = 0; seg < 8; ++seg) s += vbp[seg * 32 + t];
    vbar[t] = s;
  }
  // T[d][t] = sum_c Wq[d][c] * S[b][c][t]
  float acc[32];
#pragma unroll
  for (int d = 0; d < 32; ++d) acc[d] = 0.f;
  const float* Sb = S + (size_t)b * 65536;
  for (int c = 0; c < 256; ++c) {
    const float sv = Sb[c * 256 + t];
#pragma unroll
    for (int d = 0; d < 32; ++d) acc[d] += wq_s[d * 257 + c] * sv;
  }
  __syncthreads();
#pragma unroll
  for (int d = 0; d < 32; ++d) wq_s[d * 257 + t] = acc[d];
  __syncthreads();
  // logits[d][e] = scale * sum_c T[d][c] * Wk[e][c]
  {
    const int d = t >> 3, e0 = (t & 7) * 4;
    float l0 = 0.f, l1 = 0.f, l2 = 0.f, l3 = 0.f;
    for (int c = 0; c < 256; ++c) {
      const float tv = wq_s[d * 257 + c];
      l0 += tv * wk_s[(e0 + 0) * 257 + c];
      l1 += tv * wk_s[(e0 + 1) * 257 + c];
      l2 += tv * wk_s[(e0 + 2) * 257 + c];
      l3 += tv * wk_s[(e0 + 3) * 257 + c];
    }
    const float scale = 0.17677669529663687f;  // 1/sqrt(32)
    att[d * 33 + e0 + 0] = l0 * scale;
    att[d * 33 + e0 + 1] = l1 * scale;
    att[d * 33 + e0 + 2] = l2 * scale;
    att[d * 33 + e0 + 3] = l3 * scale;
  }
  __syncthreads();
  if (t < 32) {
    float mx = -1e30f;
#pragma unroll
    for (int e = 0; e < 32; ++e) mx = fmaxf(mx, att[t * 33 + e]);
    float sm = 0.f, xa = 0.f;
#pragma unroll
    for (int e = 0; e < 32; ++e) {
      float pe = expf(att[t * 33 + e] - mx);
      sm += pe; xa += pe * vbar[e];
    }
    xabar[b * 256 + h * 32 + t] = xa / sm;
  }
}

// out[b][o] = sigmoid(w_proj[o,:] . xabar[b,:] + b_proj[o])
__global__ __launch_bounds__(256) void kD_out(const float* __restrict__ xabar,
    const float* __restrict__ w_proj, const float* __restrict__ b_proj,
    float* __restrict__ out) {
  __shared__ float xa[256];
  const int t = threadIdx.x, b = blockIdx.x;
  xa[t] = xabar[b * 256 + t];
  __syncthreads();
  float acc = b_proj[t];
  const float4* wp = reinterpret_cast<const float4*>(w_proj + (size_t)t * 256);
  const float4* xav = reinterpret_cast<const float4*>(xa);
#pragma unroll 4
  for (int c = 0; c < 64; ++c) {
    float4 wv = wp[c], xv = xav[c];
    acc += wv.x * xv.x + wv.y * xv.y + wv.z * xv.z + wv.w * xv.w;
  }
  out[b * 256 + t] = 1.f / (1.f + expf(-acc));
}

extern "C" void kernel_launch(void* const* d_in, const int* in_sizes, int n_in,
                              void* d_out, int out_size, void* d_ws, size_t ws_size,
                              hipStream_t stream) {
  const float* x      = (const float*)d_in[0];
  const float* ln_w   = (const float*)d_in[1];
  const float* ln_b   = (const float*)d_in[2];
  const float* w_qkv  = (const float*)d_in[3];
  const float* w_proj = (const float*)d_in[4];
  const float* b_proj = (const float*)d_in[5];
  float* out = (float*)d_out;

  char* ws = (char*)d_ws;
  float* Spart = (float*)ws;                       // 256*65536*4 = 67,108,864 B
  float* xbarp = (float*)(ws + 67108864);          // 256*256*4   =    262,144 B
  float* S     = (float*)(ws + 67371008);          // 16*65536*4  =  4,194,304 B
  float* xabar = (float*)(ws + 71565312);          // 16*256*4    =     16,384 B

  kG<<<256, 1024, 0, stream>>>(x, ln_w, ln_b, Spart, xbarp);
  kR<<<1024, 256, 0, stream>>>((const float4*)Spart, (float4*)S);
  kC2<<<128, 256, 0, stream>>>(S, w_qkv, xbarp, xabar);
  kD_out<<<16, 256, 0, stream>>>(xabar, w_proj, b_proj, out);
}